// Round 3
// baseline (502.588 us; speedup 1.0000x reference)
//
#include <hip/hip_runtime.h>
#include <hip/hip_bf16.h>
#include <cmath>

// y = x[4096,8192] @ W[8192,8192]^T + b; avgpool16 -> gelu_tanh*2 -> rowmax
// Key algebra: avgpool over OUT features commutes with the GEMM:
//   pooled = x @ Wp^T  where Wp[g,:] = sum of W rows 16g..16g+15  (then /16 later)
// -> GEMM is 4096 x 512 x 8192 (16x fewer FLOPs than naive).
#define M_DIM 4096
#define N_POOL 512
#define K_DIM 8192
#define KSPLIT 8
#define K_PER (K_DIM / KSPLIT)  // 1024

typedef __bf16 bf16x8 __attribute__((ext_vector_type(8)));
typedef float floatx4 __attribute__((ext_vector_type(4)));
typedef unsigned short ushort8v __attribute__((ext_vector_type(8)));

__device__ __forceinline__ unsigned short f2bf(float f) {
  unsigned int u = __float_as_uint(f);
  return (unsigned short)((u + 0x7fffu + ((u >> 16) & 1u)) >> 16);  // RNE
}

#define WPOOL_BLOCKS 512
#define CONV_BLOCKS 2048

// Fused prep: blocks [0,512) pool W rows (f32 accum -> bf16),
// blocks [512,2560) convert x f32->bf16, block 2560 pools the bias.
// All BW-bound; one launch lets the W-stream and x-stream overlap.
__global__ __launch_bounds__(256) void prep_kernel(
    const float* __restrict__ W, unsigned short* __restrict__ Wp,
    const float4* __restrict__ src, ushort8v* __restrict__ dst, int n8,
    const float* __restrict__ b, float* __restrict__ bpool) {
  int bid = blockIdx.x;
  if (bid < WPOOL_BLOCKS) {
    // Wp[g,k] = sum_{j=16g..16g+15} W[j,k]
    int g = bid;
    const float* base = W + (size_t)g * 16 * K_DIM;
    ushort4* out = (ushort4*)(Wp + (size_t)g * K_DIM);
    for (int c4 = threadIdx.x; c4 < K_DIM / 4; c4 += blockDim.x) {
      float4 s = {0.f, 0.f, 0.f, 0.f};
#pragma unroll
      for (int j = 0; j < 16; ++j) {
        float4 v = ((const float4*)(base + (size_t)j * K_DIM))[c4];
        s.x += v.x; s.y += v.y; s.z += v.z; s.w += v.w;
      }
      ushort4 o;
      o.x = f2bf(s.x); o.y = f2bf(s.y); o.z = f2bf(s.z); o.w = f2bf(s.w);
      out[c4] = o;
    }
  } else if (bid < WPOOL_BLOCKS + CONV_BLOCKS) {
    // x fp32 -> bf16, 32B read / 16B write per thread-iter.
    int i = (bid - WPOOL_BLOCKS) * blockDim.x + threadIdx.x;
    int stride = CONV_BLOCKS * blockDim.x;
    for (; i < n8; i += stride) {
      float4 a = src[2 * i], c = src[2 * i + 1];
      ushort8v o;
      o[0] = f2bf(a.x); o[1] = f2bf(a.y); o[2] = f2bf(a.z); o[3] = f2bf(a.w);
      o[4] = f2bf(c.x); o[5] = f2bf(c.y); o[6] = f2bf(c.z); o[7] = f2bf(c.w);
      dst[i] = o;
    }
  } else {
    for (int g = threadIdx.x; g < N_POOL; g += blockDim.x) {
      float s = 0.f;
#pragma unroll
      for (int i = 0; i < 16; ++i) s += b[g * 16 + i];
      bpool[g] = s;
    }
  }
}

// Split-K GEMM: C_part[kz] = x[:, kz*1024:(kz+1)*1024] @ Wp[:, same]^T
// 128x128 tile, BK=64, 4 waves of 64x64, mfma_f32_16x16x32_bf16,
// global_load_lds width=16 staging with XOR bank swizzle (proven structure).
// 1D grid of 1024, XCD-aware decode: kz == xcd, so each XCD's Wp k-slice
// (1 MiB) is L2-resident; 4 blocks/CU (16 waves/CU) for latency hiding.
__global__ __launch_bounds__(256) void gemm_splitk(
    const unsigned short* __restrict__ xb,   // [4096][8192] bf16
    const unsigned short* __restrict__ wp,   // [512][8192] bf16
    float* __restrict__ part)                // [KSPLIT][4096][512] fp32
{
  __shared__ __align__(16) unsigned short As[128 * 64];
  __shared__ __align__(16) unsigned short Bs[128 * 64];

  const int tid = threadIdx.x;
  const int L = tid & 63;
  const int w = tid >> 6;
  const int wm = w & 1, wn = w >> 1;
  const int lane15 = L & 15, quad = L >> 4;

  // id -> (kz, bn, bm): xcd = id%8 (HW round-robin), kz pinned per XCD.
  const int id = blockIdx.x;
  const int kz = id & 7;
  const int c = id >> 3;     // 0..127 within XCD
  const int bn = c & 3, bm = c >> 2;

  const int srow = w * 32 + (L >> 3);
  const int schunk = ((L & 7) ^ ((L >> 3) & 7)) * 8;
  const unsigned short* ga = xb + (size_t)(bm * 128 + srow) * K_DIM + kz * K_PER + schunk;
  const unsigned short* gb = wp + (size_t)(bn * 128 + srow) * K_DIM + kz * K_PER + schunk;
  unsigned short* lA = As + (w * 32) * 64;
  unsigned short* lB = Bs + (w * 32) * 64;

  floatx4 acc[4][4];
#pragma unroll
  for (int t = 0; t < 4; ++t)
#pragma unroll
    for (int u = 0; u < 4; ++u) acc[t][u] = (floatx4)0.f;

  const bf16x8* Av = (const bf16x8*)As;
  const bf16x8* Bv = (const bf16x8*)Bs;

  for (int kk = 0; kk < K_PER / 64; ++kk) {
#pragma unroll
    for (int i = 0; i < 4; ++i) {
      __builtin_amdgcn_global_load_lds(
          (const __attribute__((address_space(1))) void*)(ga + (size_t)(i * 8) * K_DIM),
          (__attribute__((address_space(3))) void*)(lA + i * 8 * 64), 16, 0, 0);
    }
#pragma unroll
    for (int i = 0; i < 4; ++i) {
      __builtin_amdgcn_global_load_lds(
          (const __attribute__((address_space(1))) void*)(gb + (size_t)(i * 8) * K_DIM),
          (__attribute__((address_space(3))) void*)(lB + i * 8 * 64), 16, 0, 0);
    }
    ga += 64; gb += 64;
    __syncthreads();

#pragma unroll
    for (int ks = 0; ks < 2; ++ks) {
      bf16x8 af[4], bfr[4];
#pragma unroll
      for (int t = 0; t < 4; ++t) {
        int r = wm * 64 + t * 16 + lane15;
        af[t] = Av[r * 8 + ((ks * 4 + quad) ^ (lane15 & 7))];
      }
#pragma unroll
      for (int u = 0; u < 4; ++u) {
        int r = wn * 64 + u * 16 + lane15;
        bfr[u] = Bv[r * 8 + ((ks * 4 + quad) ^ (lane15 & 7))];
      }
#pragma unroll
      for (int t = 0; t < 4; ++t)
#pragma unroll
        for (int u = 0; u < 4; ++u)
          acc[t][u] = __builtin_amdgcn_mfma_f32_16x16x32_bf16(af[t], bfr[u],
                                                              acc[t][u], 0, 0, 0);
    }
    __syncthreads();
  }

  // C/D layout: col = lane&15, row = quad*4 + reg.
  float* cp = part + (size_t)kz * M_DIM * N_POOL;
  const int row_base = bm * 128 + wm * 64;
  const int col_base = bn * 128 + wn * 64;
#pragma unroll
  for (int t = 0; t < 4; ++t)
#pragma unroll
    for (int u = 0; u < 4; ++u) {
      int col = col_base + u * 16 + lane15;
#pragma unroll
      for (int r = 0; r < 4; ++r) {
        int row = row_base + t * 16 + quad * 4 + r;
        cp[(size_t)row * N_POOL + col] = acc[t][u][r];
      }
    }
}

__device__ __forceinline__ float gelu2(float s) {
  float p = s * 0.0625f;  // /16 avgpool
  float t = tanhf(0.7978845608028654f * (p + 0.044715f * p * p * p));
  return p * (1.0f + t);  // gelu_tanh(p) * SCALE(=2)
}

// 4 rows per block (one wave each), float4 reads of part.
__global__ void finalize(const float* __restrict__ part,
                         const float* __restrict__ bpool,
                         float* __restrict__ out) {
  const int w = threadIdx.x >> 6, lane = threadIdx.x & 63;
  const int row = blockIdx.x * 4 + w;
  const float4* bp4 = (const float4*)bpool;
  float mx = -INFINITY;
#pragma unroll
  for (int j = 0; j < 2; ++j) {
    int g4 = lane + j * 64;  // float4 index, 0..127
    float4 s = bp4[g4];
#pragma unroll
    for (int kz = 0; kz < KSPLIT; ++kz) {
      float4 v = ((const float4*)(part + (size_t)kz * M_DIM * N_POOL +
                                  (size_t)row * N_POOL))[g4];
      s.x += v.x; s.y += v.y; s.z += v.z; s.w += v.w;
    }
    mx = fmaxf(mx, fmaxf(fmaxf(gelu2(s.x), gelu2(s.y)),
                         fmaxf(gelu2(s.z), gelu2(s.w))));
  }
#pragma unroll
  for (int sh = 32; sh >= 1; sh >>= 1) mx = fmaxf(mx, __shfl_xor(mx, sh));
  if (lane == 0) out[row] = mx;
}

extern "C" void kernel_launch(void* const* d_in, const int* in_sizes, int n_in,
                              void* d_out, int out_size, void* d_ws, size_t ws_size,
                              hipStream_t stream) {
  const float* x = (const float*)d_in[0];  // [4096,8192]
  const float* W = (const float*)d_in[1];  // [8192,8192]
  const float* b = (const float*)d_in[2];  // [8192]
  float* out = (float*)d_out;              // [4096]

  // Workspace layout (no overlaps):
  //   xb    [0,          67108864)   64 MiB  bf16 x
  //   Wp    [67108864,   75497472)    8 MiB  bf16 pooled W
  //   part  [75497472,  142606336)   64 MiB  fp32 split-K partials (KSPLIT=8)
  //   bpool [142606336, 142608384)    2 KiB  fp32 pooled bias
  char* ws = (char*)d_ws;
  unsigned short* xb = (unsigned short*)ws;
  unsigned short* Wp = (unsigned short*)(ws + (size_t)67108864);
  float* part = (float*)(ws + (size_t)75497472);
  float* bpool = (float*)(ws + (size_t)142606336);

  prep_kernel<<<WPOOL_BLOCKS + CONV_BLOCKS + 1, 256, 0, stream>>>(
      W, Wp, (const float4*)x, (ushort8v*)xb, (M_DIM * K_DIM) / 8, b, bpool);

  gemm_splitk<<<1024, 256, 0, stream>>>(xb, Wp, part);

  finalize<<<M_DIM / 4, 256, 0, stream>>>(part, bpool, out);
}

// Round 4
// 475.251 us; speedup vs baseline: 1.0575x; 1.0575x over previous
//
#include <hip/hip_runtime.h>
#include <hip/hip_bf16.h>
#include <cmath>

// y = x[4096,8192] @ W[8192,8192]^T + b; avgpool16 -> gelu_tanh*2 -> rowmax
// Key algebra: avgpool over OUT features commutes with the GEMM:
//   pooled = x @ Wp^T  where Wp[g,:] = sum of W rows 16g..16g+15  (then /16 later)
// -> GEMM is 4096 x 512 x 8192 (16x fewer FLOPs than naive).
// This version fuses the x f32->bf16 conversion INTO the GEMM A-staging
// (reg-staged A with v_cvt_pk_bf16_f32), eliminating the xb buffer.
#define M_DIM 4096
#define N_POOL 512
#define K_DIM 8192
#define KSPLIT 4
#define K_PER (K_DIM / KSPLIT)  // 2048

typedef __bf16 bf16x8 __attribute__((ext_vector_type(8)));
typedef float floatx4 __attribute__((ext_vector_type(4)));

__device__ __forceinline__ unsigned short f2bf(float f) {
  unsigned int u = __float_as_uint(f);
  return (unsigned short)((u + 0x7fffu + ((u >> 16) & 1u)) >> 16);  // RNE
}

// Prep: blocks [0,512) pool W rows (f32 accum -> bf16 Wp); block 512 pools bias.
__global__ __launch_bounds__(256) void prep_kernel(
    const float* __restrict__ W, unsigned short* __restrict__ Wp,
    const float* __restrict__ b, float* __restrict__ bpool) {
  int bid = blockIdx.x;
  if (bid < N_POOL) {
    int g = bid;
    const float* base = W + (size_t)g * 16 * K_DIM;
    ushort4* out = (ushort4*)(Wp + (size_t)g * K_DIM);
    for (int c4 = threadIdx.x; c4 < K_DIM / 4; c4 += blockDim.x) {
      float4 s = {0.f, 0.f, 0.f, 0.f};
#pragma unroll
      for (int j = 0; j < 16; ++j) {
        float4 v = ((const float4*)(base + (size_t)j * K_DIM))[c4];
        s.x += v.x; s.y += v.y; s.z += v.z; s.w += v.w;
      }
      ushort4 o;
      o.x = f2bf(s.x); o.y = f2bf(s.y); o.z = f2bf(s.z); o.w = f2bf(s.w);
      out[c4] = o;
    }
  } else {
    for (int g = threadIdx.x; g < N_POOL; g += blockDim.x) {
      float s = 0.f;
#pragma unroll
      for (int i = 0; i < 16; ++i) s += b[g * 16 + i];
      bpool[g] = s;
    }
  }
}

// Split-K GEMM: C_part[kz] = x[:, kz*2048:(kz+1)*2048] @ Wp[:, same]^T
// 128x128 tile, BK=64, 4 waves of 64x64, mfma_f32_16x16x32_bf16.
// A: reg-staged from f32 x (fused conversion, XOR-swizzled LDS layout
//    identical to the proven global_load_lds image).
// B: global_load_lds width=16 with pre-swizzled global source.
// 1D grid of 512, XCD-aware decode: kz pinned to an XCD pair so the
// per-kz Wp slice (1 MiB/XCD) is L2-resident.
__global__ __launch_bounds__(256) void gemm_splitk(
    const float* __restrict__ x,             // [4096][8192] f32
    const unsigned short* __restrict__ wp,   // [512][8192] bf16
    float* __restrict__ part)                // [KSPLIT][4096][512] fp32
{
  __shared__ __align__(16) unsigned short As[128 * 64];
  __shared__ __align__(16) unsigned short Bs[128 * 64];

  const int tid = threadIdx.x;
  const int L = tid & 63;
  const int w = tid >> 6;
  const int wm = w & 1, wn = w >> 1;
  const int lane15 = L & 15, quad = L >> 4;

  // id -> (kz, bn, bm): xcd = id%8 (HW round-robin), 2 XCDs per kz value.
  const int id = blockIdx.x;
  const int xcd = id & 7;
  const int c = id >> 3;               // 0..63 within XCD
  const int kz = xcd >> 1;             // 0..3
  const int j = (c << 1) | (xcd & 1);  // 0..127 within kz
  const int bn = j & 3, bm = j >> 2;

  const int srow = w * 32 + (L >> 3);                 // staging row (i adds 8)
  const int gcol8 = (L & 7) ^ ((L >> 3) & 7);         // swizzled global chunk
  const float* gx = x + (size_t)(bm * 128 + srow) * K_DIM + kz * K_PER + gcol8 * 8;
  const unsigned short* gb = wp + (size_t)(bn * 128 + srow) * K_DIM + kz * K_PER + gcol8 * 8;
  unsigned short* wA = As + srow * 64 + (L & 7) * 8;  // linear LDS dest (16B aligned)
  unsigned short* lB = Bs + (w * 32) * 64;

  floatx4 acc[4][4];
#pragma unroll
  for (int t = 0; t < 4; ++t)
#pragma unroll
    for (int u = 0; u < 4; ++u) acc[t][u] = (floatx4)0.f;

  const bf16x8* Av = (const bf16x8*)As;
  const bf16x8* Bv = (const bf16x8*)Bs;

  for (int kk = 0; kk < K_PER / 64; ++kk) {
    // A: load 8 f32 per row-chunk (2x dwordx4), convert in-reg, LDS-write.
    float4 fa[4], fb4[4];
#pragma unroll
    for (int i = 0; i < 4; ++i) {
      const float4* p = (const float4*)(gx + (size_t)(i * 8) * K_DIM);
      fa[i] = p[0];
      fb4[i] = p[1];
    }
    // B: direct global->LDS DMA.
#pragma unroll
    for (int i = 0; i < 4; ++i) {
      __builtin_amdgcn_global_load_lds(
          (const __attribute__((address_space(1))) void*)(gb + (size_t)(i * 8) * K_DIM),
          (__attribute__((address_space(3))) void*)(lB + i * 8 * 64), 16, 0, 0);
    }
    gx += 64; gb += 64;
#pragma unroll
    for (int i = 0; i < 4; ++i) {
      uint4 o;
      asm("v_cvt_pk_bf16_f32 %0, %1, %2" : "=v"(o.x) : "v"(fa[i].x), "v"(fa[i].y));
      asm("v_cvt_pk_bf16_f32 %0, %1, %2" : "=v"(o.y) : "v"(fa[i].z), "v"(fa[i].w));
      asm("v_cvt_pk_bf16_f32 %0, %1, %2" : "=v"(o.z) : "v"(fb4[i].x), "v"(fb4[i].y));
      asm("v_cvt_pk_bf16_f32 %0, %1, %2" : "=v"(o.w) : "v"(fb4[i].z), "v"(fb4[i].w));
      *(uint4*)(wA + (size_t)(i * 8) * 64) = o;  // ds_write_b128, bank-sweep clean
    }
    __syncthreads();  // drains vmcnt (B DMA) + lgkmcnt (A ds_write)

#pragma unroll
    for (int ks = 0; ks < 2; ++ks) {
      bf16x8 af[4], bfr[4];
#pragma unroll
      for (int t = 0; t < 4; ++t) {
        int r = wm * 64 + t * 16 + lane15;
        af[t] = Av[r * 8 + ((ks * 4 + quad) ^ (lane15 & 7))];
      }
#pragma unroll
      for (int u = 0; u < 4; ++u) {
        int r = wn * 64 + u * 16 + lane15;
        bfr[u] = Bv[r * 8 + ((ks * 4 + quad) ^ (lane15 & 7))];
      }
#pragma unroll
      for (int t = 0; t < 4; ++t)
#pragma unroll
        for (int u = 0; u < 4; ++u)
          acc[t][u] = __builtin_amdgcn_mfma_f32_16x16x32_bf16(af[t], bfr[u],
                                                              acc[t][u], 0, 0, 0);
    }
    __syncthreads();
  }

  // C/D layout: col = lane&15, row = quad*4 + reg.
  float* cp = part + (size_t)kz * M_DIM * N_POOL;
  const int row_base = bm * 128 + wm * 64;
  const int col_base = bn * 128 + wn * 64;
#pragma unroll
  for (int t = 0; t < 4; ++t)
#pragma unroll
    for (int u = 0; u < 4; ++u) {
      int col = col_base + u * 16 + lane15;
#pragma unroll
      for (int r = 0; r < 4; ++r) {
        int row = row_base + t * 16 + quad * 4 + r;
        cp[(size_t)row * N_POOL + col] = acc[t][u][r];
      }
    }
}

__device__ __forceinline__ float gelu2(float s) {
  float p = s * 0.0625f;  // /16 avgpool
  float t = tanhf(0.7978845608028654f * (p + 0.044715f * p * p * p));
  return p * (1.0f + t);  // gelu_tanh(p) * SCALE(=2)
}

// 4 rows per block (one wave each), float4 reads of part.
__global__ void finalize(const float* __restrict__ part,
                         const float* __restrict__ bpool,
                         float* __restrict__ out) {
  const int w = threadIdx.x >> 6, lane = threadIdx.x & 63;
  const int row = blockIdx.x * 4 + w;
  const float4* bp4 = (const float4*)bpool;
  float mx = -INFINITY;
#pragma unroll
  for (int j = 0; j < 2; ++j) {
    int g4 = lane + j * 64;  // float4 index, 0..127
    float4 s = bp4[g4];
#pragma unroll
    for (int kz = 0; kz < KSPLIT; ++kz) {
      float4 v = ((const float4*)(part + (size_t)kz * M_DIM * N_POOL +
                                  (size_t)row * N_POOL))[g4];
      s.x += v.x; s.y += v.y; s.z += v.z; s.w += v.w;
    }
    mx = fmaxf(mx, fmaxf(fmaxf(gelu2(s.x), gelu2(s.y)),
                         fmaxf(gelu2(s.z), gelu2(s.w))));
  }
#pragma unroll
  for (int sh = 32; sh >= 1; sh >>= 1) mx = fmaxf(mx, __shfl_xor(mx, sh));
  if (lane == 0) out[row] = mx;
}

extern "C" void kernel_launch(void* const* d_in, const int* in_sizes, int n_in,
                              void* d_out, int out_size, void* d_ws, size_t ws_size,
                              hipStream_t stream) {
  const float* x = (const float*)d_in[0];  // [4096,8192]
  const float* W = (const float*)d_in[1];  // [8192,8192]
  const float* b = (const float*)d_in[2];  // [8192]
  float* out = (float*)d_out;              // [4096]

  // Workspace layout (no overlaps; xb eliminated):
  //   Wp    [0,         8388608)    8 MiB  bf16 pooled W
  //   part  [8388608,  41943040)   32 MiB  fp32 split-K partials (KSPLIT=4)
  //   bpool [41943040, 41945088)    2 KiB  fp32 pooled bias
  char* ws = (char*)d_ws;
  unsigned short* Wp = (unsigned short*)ws;
  float* part = (float*)(ws + (size_t)8388608);
  float* bpool = (float*)(ws + (size_t)41943040);

  prep_kernel<<<N_POOL + 1, 256, 0, stream>>>(W, Wp, b, bpool);

  gemm_splitk<<<512, 256, 0, stream>>>(x, Wp, part);

  finalize<<<M_DIM / 4, 256, 0, stream>>>(part, bpool, out);
}